// Round 4
// baseline (445.447 us; speedup 1.0000x reference)
//
#include <hip/hip_runtime.h>
#include <hip/hip_bf16.h>
#include <math.h>

// Problem constants
#define BD 8          // batch
#define SN 2048       // sequence length N
#define DM 1024       // d_model
#define NH 16         // heads
#define HD 64         // head dim
#define NS 11         // scales
#define NTAP 24       // unique wavelet offsets across 11 scales
#define PAD 3072      // max lookback = 3*2^10

typedef __attribute__((ext_vector_type(8))) short short8;
typedef __attribute__((ext_vector_type(4))) float floatx4;

// unique offsets (3-t)<<j, sorted (constexpr -> folds to immediates in addressing)
constexpr int OFFS[NTAP] = {0, 1, 2, 3, 4, 6, 8, 12, 16, 24, 32, 48, 64, 96,
                            128, 192, 256, 384, 512, 768, 1024, 1536, 2048, 3072};

// async global->LDS, 16B per lane; LDS dest = wave-uniform base + lane*16
__device__ __forceinline__ void async_load16(const void* g, void* lds) {
    __builtin_amdgcn_global_load_lds(
        (const __attribute__((address_space(1))) void*)g,
        (__attribute__((address_space(3))) void*)lds,
        16, 0, 0);
}

__device__ __forceinline__ float bf2f(int v) {
    union { unsigned u; float f; } cv;
    cv.u = ((unsigned)v & 0xffffu) << 16;
    return cv.f;
}

__device__ __forceinline__ unsigned short f2bfbits(float x) {
    union { __hip_bfloat16 h; unsigned short u; } cv;
    cv.h = __float2bfloat16(x);
    return cv.u;
}

// ---------------------------------------------------------------------------
// fp32 -> bf16 convert (vectorized by 4)
// ---------------------------------------------------------------------------
__global__ __launch_bounds__(256) void f2bf_kernel(const float* __restrict__ src,
                                                   __hip_bfloat16* __restrict__ dst,
                                                   int n4) {
    int i = blockIdx.x * 256 + threadIdx.x;
    if (i < n4) {
        const float4 v = reinterpret_cast<const float4*>(src)[i];
        union { __hip_bfloat16 h[4]; uint2 u; } cv;
        cv.h[0] = __float2bfloat16(v.x);
        cv.h[1] = __float2bfloat16(v.y);
        cv.h[2] = __float2bfloat16(v.z);
        cv.h[3] = __float2bfloat16(v.w);
        reinterpret_cast<uint2*>(dst)[i] = cv.u;
    }
}

// ---------------------------------------------------------------------------
// prep: softmaxes + per-head tap table + kg bias concat
// ---------------------------------------------------------------------------
__global__ void prep_kernel(const float* __restrict__ scale_gain,
                            const float* __restrict__ field_coupling,
                            const float* __restrict__ qkv_b,
                            const float* __restrict__ gate_b,
                            float* __restrict__ wtab,    // [NTAP][NH]
                            float* __restrict__ cw,      // [NH][NH]
                            float* __restrict__ biascat) // [2048]: k bias | gate bias
{
    const float D4[4] = {0.4829629131445341f, 0.8365163037378079f,
                         0.2241438680420134f, -0.1294095225512604f};
    int t = threadIdx.x;
    if (t < NH) {
        float g[NS];
        float m = -1e30f;
        for (int j = 0; j < NS; ++j) m = fmaxf(m, scale_gain[j * NH + t]);
        float s = 0.f;
        for (int j = 0; j < NS; ++j) { g[j] = expf(scale_gain[j * NH + t] - m); s += g[j]; }
        float inv = 1.f / s;
        for (int j = 0; j < NS; ++j) g[j] *= inv;
        for (int i = 0; i < NTAP; ++i) {
            float w = 0.f;
            for (int j = 0; j < NS; ++j)
                for (int tt = 0; tt < 4; ++tt)
                    if (((3 - tt) << j) == OFFS[i]) w += g[j] * D4[tt];
            wtab[i * NH + t] = w;
        }
    } else if (t < 2 * NH) {
        int r = t - NH;
        float m = -1e30f;
        for (int j = 0; j < NH; ++j) m = fmaxf(m, field_coupling[r * NH + j]);
        float e[NH]; float s = 0.f;
        for (int j = 0; j < NH; ++j) { e[j] = expf(field_coupling[r * NH + j] - m); s += e[j]; }
        float inv = 1.f / s;
        for (int j = 0; j < NH; ++j) cw[r * NH + j] = e[j] * inv;
    }
    for (int i = t; i < 2048; i += 256)
        biascat[i] = (i < 1024) ? qkv_b[1024 + i] : gate_b[i - 1024];
}

// ---------------------------------------------------------------------------
// 256x256 8-phase bf16 MFMA GEMM (plain-HIP port of the m201 schedule).
// 512 thr / 8 waves (2Mx4N), BK=64, 128KB LDS double-buffered, per-wave 128x64.
// v2 fix (m141 lesson): NO sched_barrier(0) order-pins — raw s_barrier pairs
// only; compiler keeps its own fine-grained lgkmcnt for ds_read->MFMA deps and
// software-pipelines across phases. Counted vmcnt(4) at phases 4/8 (never 0 in
// steady state). Race ledger (unchanged, verified passing in round 3):
// every phase's ds_reads are consumed by that phase's MFMA before its end
// barrier, and stages only issue after that barrier; buffer-reuse points are
// anchored by the counted vmcnt waits.
// mode 0: C fp32 = A@Bw^T + bias[col]                  (out GEMM)
// mode 1: C bf16 = A@Bw^T + bias[row]                  (v GEMM, swapped operands)
// mode 2: kg fused: cols<1024 -> kmag[h][r] = ||k+bias|| (no C write);
//         cols>=1024 -> gate bf16 = sigmoid(. + bias[col]), stored at col-1024
// ---------------------------------------------------------------------------

#define PHASE_SYNC() do { \
    __builtin_amdgcn_s_barrier(); \
    asm volatile("s_waitcnt lgkmcnt(0)" ::: "memory"); \
} while (0)

#define PHASE_END() do { \
    __builtin_amdgcn_s_barrier(); \
} while (0)

// stage one half-tile (128 rows x 64 k) of operand GP (tile-row base applied)
// into LDS short-base LB; 2 x global_load_lds per thread, linear dest,
// source k-chunk pre-swizzled by (row&7) (same involution as the reads).
#define STAGE(GP, H, KT, LB) do { \
    _Pragma("unroll") \
    for (int jj = 0; jj < 2; ++jj) { \
        const int grow_ = (H) * 128 + jj * 64 + srow; \
        async_load16((GP) + (size_t)grow_ * K + (KT) + gk8, \
                     &S[(LB) + ((H) * 128 + jj * 64 + wid8) * 64]); \
    } \
} while (0)

#define READ_A(AV, P, MF0) do { \
    _Pragma("unroll") \
    for (int mm = 0; mm < 4; ++mm) { \
        const int off_ = (P) * 32768 + abase + ((MF0) + mm) * 1024; \
        AV[mm][0] = *reinterpret_cast<const short8*>(&S[off_ + sw0]); \
        AV[mm][1] = *reinterpret_cast<const short8*>(&S[off_ + sw1]); \
    } \
} while (0)

#define READ_B(P, NF0) do { \
    _Pragma("unroll") \
    for (int nn = 0; nn < 2; ++nn) { \
        const int off_ = (P) * 32768 + bbase + ((NF0) + nn) * 1024; \
        bfr[nn][0] = *reinterpret_cast<const short8*>(&S[off_ + sw0]); \
        bfr[nn][1] = *reinterpret_cast<const short8*>(&S[off_ + sw1]); \
    } \
} while (0)

#define MFMA_Q(AV, MF0, NF0) do { \
    __builtin_amdgcn_s_setprio(1); \
    _Pragma("unroll") \
    for (int mm = 0; mm < 4; ++mm) \
        _Pragma("unroll") \
        for (int nn = 0; nn < 2; ++nn) \
            _Pragma("unroll") \
            for (int hh = 0; hh < 2; ++hh) \
                acc[(MF0) + mm][(NF0) + nn] = __builtin_amdgcn_mfma_f32_16x16x32_bf16( \
                    AV[mm][hh], bfr[nn][hh], acc[(MF0) + mm][(NF0) + nn], 0, 0, 0); \
    __builtin_amdgcn_s_setprio(0); \
} while (0)

__global__ __launch_bounds__(512, 2) void gemm256_kernel(
    const __hip_bfloat16* __restrict__ A,
    const __hip_bfloat16* __restrict__ Bw,
    void* __restrict__ Cout,
    const float* __restrict__ bias,
    float* __restrict__ kmag,
    int M, int Nn, int K, int mode) {
    __shared__ short S[65536];   // 128 KB: [p][A 16384 | B 16384] shorts

    const int tid = threadIdx.x;
    const int wid = tid >> 6;
    const int ln  = tid & 63;
    const int m0 = blockIdx.y * 256;
    const int n0 = blockIdx.x * 256;

    // staging per-thread constants
    const int srow = tid >> 3;                       // 0..63
    const int gk8  = ((tid & 7) ^ (srow & 7)) * 8;   // swizzled k-chunk (elems)
    const int wid8 = wid * 8;

    // compute per-thread constants
    const int lrow = ln & 15, quad = ln >> 4;
    const int wm = (wid >> 2) * 128;
    const int wn = (wid & 3) * 64;
    const int sw0 = (quad ^ (lrow & 7)) * 8;         // k-half 0 chunk (shorts)
    const int sw1 = ((4 + quad) ^ (lrow & 7)) * 8;   // k-half 1 chunk
    const int abase = (wm + lrow) * 64;
    const int bbase = 16384 + (wn + lrow) * 64;

    const __hip_bfloat16* Ab = A + (size_t)m0 * K;
    const __hip_bfloat16* Bb = Bw + (size_t)n0 * K;

    floatx4 acc[8][4];
    #pragma unroll
    for (int a = 0; a < 8; ++a)
        #pragma unroll
        for (int b = 0; b < 4; ++b) acc[a][b] = (floatx4){0.f, 0.f, 0.f, 0.f};
    short8 a01[4][2], a23[4][2], bfr[2][2];

    const int I = K >> 7;   // iterations, 2 K-tiles each (K=1024 -> 8)

    // prologue: tile0 (A+B) -> buf0, tile1 A -> buf1; keep tile1.A in flight
    STAGE(Ab, 0, 0, 0);
    STAGE(Ab, 1, 0, 0);
    STAGE(Bb, 0, 0, 16384);
    STAGE(Bb, 1, 0, 16384);
    STAGE(Ab, 0, 64, 32768);
    STAGE(Ab, 1, 64, 32768);
    asm volatile("s_waitcnt vmcnt(4)" ::: "memory");
    __builtin_amdgcn_s_barrier();

    for (int i = 0; i < I; ++i) {
        const int t1k = (2 * i + 1) * 64;
        const int t2k = (2 * i + 2) * 64;
        const int t3k = (2 * i + 3) * 64;
        const bool notlast = (i < I - 1);

        // ---- tile 2i from buf0 ----
        // ph1
        READ_A(a01, 0, 0); READ_B(0, 0);
        STAGE(Bb, 0, t1k, 49152);
        PHASE_SYNC();
        MFMA_Q(a01, 0, 0);
        PHASE_END();
        // ph2
        READ_A(a23, 0, 4); READ_B(0, 2);
        STAGE(Bb, 1, t1k, 49152);
        PHASE_SYNC();
        MFMA_Q(a01, 0, 2);
        PHASE_END();
        // ph3
        READ_B(0, 0);
        if (notlast) STAGE(Ab, 0, t2k, 0);
        PHASE_SYNC();
        MFMA_Q(a23, 4, 0);
        PHASE_END();
        // ph4
        READ_B(0, 2);
        if (notlast) STAGE(Ab, 1, t2k, 0);
        PHASE_SYNC();
        MFMA_Q(a23, 4, 2);
        if (notlast) { asm volatile("s_waitcnt vmcnt(4)" ::: "memory"); }
        else         { asm volatile("s_waitcnt vmcnt(0)" ::: "memory"); }
        PHASE_END();

        // ---- tile 2i+1 from buf1 ----
        // ph5
        READ_A(a01, 1, 0); READ_B(1, 0);
        if (notlast) STAGE(Bb, 0, t2k, 16384);
        PHASE_SYNC();
        MFMA_Q(a01, 0, 0);
        PHASE_END();
        // ph6
        READ_A(a23, 1, 4); READ_B(1, 2);
        if (notlast) STAGE(Bb, 1, t2k, 16384);
        PHASE_SYNC();
        MFMA_Q(a01, 0, 2);
        PHASE_END();
        // ph7
        READ_B(1, 0);
        if (notlast) STAGE(Ab, 0, t3k, 32768);
        PHASE_SYNC();
        MFMA_Q(a23, 4, 0);
        PHASE_END();
        // ph8
        READ_B(1, 2);
        if (notlast) STAGE(Ab, 1, t3k, 32768);
        PHASE_SYNC();
        MFMA_Q(a23, 4, 2);
        if (notlast) { asm volatile("s_waitcnt vmcnt(4)" ::: "memory"); }
        PHASE_END();
    }

    if (mode == 2 && n0 < 1024) {
        // k-norm epilogue: each wave's 64 cols = exactly one head
        const int h = (n0 + wn) >> 6;
        #pragma unroll
        for (int mf = 0; mf < 8; ++mf) {
            #pragma unroll
            for (int i4 = 0; i4 < 4; ++i4) {
                float ss = 0.f;
                #pragma unroll
                for (int nf = 0; nf < 4; ++nf) {
                    const float v = acc[mf][nf][i4] + bias[n0 + wn + nf * 16 + lrow];
                    ss += v * v;
                }
                ss += __shfl_xor(ss, 1);
                ss += __shfl_xor(ss, 2);
                ss += __shfl_xor(ss, 4);
                ss += __shfl_xor(ss, 8);
                if (lrow == 0) {
                    const int r = m0 + wm + mf * 16 + quad * 4 + i4;
                    kmag[h * (BD * SN) + r] = sqrtf(ss);
                }
            }
        }
        return;
    }

    #pragma unroll
    for (int mf = 0; mf < 8; ++mf) {
        #pragma unroll
        for (int nf = 0; nf < 4; ++nf) {
            const int col = n0 + wn + nf * 16 + lrow;
            float bv = 0.f;
            if (bias && mode != 1) bv = bias[col];
            #pragma unroll
            for (int i4 = 0; i4 < 4; ++i4) {
                const int row = m0 + wm + mf * 16 + quad * 4 + i4;
                float val = acc[mf][nf][i4] + bv;
                if (mode == 1 && bias) val += bias[row];
                if (mode == 0) {
                    ((float*)Cout)[(size_t)row * Nn + col] = val;
                } else if (mode == 1) {
                    ((__hip_bfloat16*)Cout)[(size_t)row * Nn + col] = __float2bfloat16(val);
                } else { // mode 2 gate region
                    val = 1.f / (1.f + expf(-val));
                    ((__hip_bfloat16*)Cout)[(size_t)row * 1024 + (col - 1024)] =
                        __float2bfloat16(val);
                }
            }
        }
    }
}

#undef PHASE_SYNC
#undef PHASE_END
#undef STAGE
#undef READ_A
#undef READ_B
#undef MFMA_Q

// ---------------------------------------------------------------------------
// wavelet v2: per (b,c) row; zero-padded LDS row + 24-tap table.
// Each thread computes 4 consecutive outputs via ds_read_b128 quad loads.
// ---------------------------------------------------------------------------
__global__ __launch_bounds__(256) void wavelet_kernel(const __hip_bfloat16* __restrict__ fieldv,
                                                      const float* __restrict__ kmag,
                                                      const float* __restrict__ wtab,
                                                      __hip_bfloat16* __restrict__ wave) {
    const int bc = blockIdx.x;          // b*1024 + c
    const int b = bc >> 10;
    const int c = bc & (DM - 1);
    const int h = c >> 6;
    __shared__ float row[PAD + SN];     // 20 KB
    const int t = threadIdx.x;

    // tap weights: uniform per block -> scalar loads
    float w[NTAP];
    #pragma unroll
    for (int i = 0; i < NTAP; ++i) w[i] = wtab[i * NH + h];

    // zero pad region: 3072 floats = 768 float4
    {
        float4* r4 = reinterpret_cast<float4*>(row);
        const float4 zv = {0.f, 0.f, 0.f, 0.f};
        #pragma unroll
        for (int i = 0; i < 3; ++i) r4[t + i * 256] = zv;
    }
    // fill: 8 elements per thread (vectorized bf16 load * fp32 kmag)
    {
        const __hip_bfloat16* src = fieldv + (size_t)c * (BD * SN) + b * SN;
        const float* mag = kmag + (size_t)h * (BD * SN) + b * SN;
        const int i = t * 8;
        const short8 s = *reinterpret_cast<const short8*>(src + i);
        const float4 m0 = *reinterpret_cast<const float4*>(mag + i);
        const float4 m1 = *reinterpret_cast<const float4*>(mag + i + 4);
        float4 o0, o1;
        o0.x = bf2f(s[0]) * m0.x; o0.y = bf2f(s[1]) * m0.y;
        o0.z = bf2f(s[2]) * m0.z; o0.w = bf2f(s[3]) * m0.w;
        o1.x = bf2f(s[4]) * m1.x; o1.y = bf2f(s[5]) * m1.y;
        o1.z = bf2f(s[6]) * m1.z; o1.w = bf2f(s[7]) * m1.w;
        *reinterpret_cast<float4*>(&row[PAD + i]) = o0;
        *reinterpret_cast<float4*>(&row[PAD + i + 4]) = o1;
    }
    __syncthreads();

    __hip_bfloat16* dst = wave + (size_t)bc * SN;
    #pragma unroll
    for (int pass = 0; pass < 2; ++pass) {
        const int n = (pass * 256 + t) * 4;
        const float* bp = &row[PAD + n];
        const float4 qc = *reinterpret_cast<const float4*>(bp);       // row[n..n+3]
        const float4 qb = *reinterpret_cast<const float4*>(bp - 4);   // row[n-4..n-1]
        const float4 qa = *reinterpret_cast<const float4*>(bp - 8);   // row[n-8..n-5]
        float a0, a1, a2, a3;
        a0 = w[0] * qc.x; a1 = w[0] * qc.y; a2 = w[0] * qc.z; a3 = w[0] * qc.w;
        a0 += w[1] * qb.w; a1 += w[1] * qc.x; a2 += w[1] * qc.y; a3 += w[1] * qc.z;
        a0 += w[2] * qb.z; a1 += w[2] * qb.w; a2 += w[2] * qc.x; a3 += w[2] * qc.y;
        a0 += w[3] * qb.y; a1 += w[3] * qb.z; a2 += w[3] * qb.w; a3 += w[3] * qc.x;
        a0 += w[4] * qb.x; a1 += w[4] * qb.y; a2 += w[4] * qb.z; a3 += w[4] * qb.w;
        a0 += w[5] * qa.z; a1 += w[5] * qa.w; a2 += w[5] * qb.x; a3 += w[5] * qb.y;
        a0 += w[6] * qa.x; a1 += w[6] * qa.y; a2 += w[6] * qa.z; a3 += w[6] * qa.w;
        #pragma unroll
        for (int i = 7; i < NTAP; ++i) {
            const float4 q = *reinterpret_cast<const float4*>(bp - OFFS[i]);
            a0 += w[i] * q.x; a1 += w[i] * q.y; a2 += w[i] * q.z; a3 += w[i] * q.w;
        }
        union { __hip_bfloat16 hh[4]; uint2 u; } cv;
        cv.hh[0] = __float2bfloat16(a0); cv.hh[1] = __float2bfloat16(a1);
        cv.hh[2] = __float2bfloat16(a2); cv.hh[3] = __float2bfloat16(a3);
        *reinterpret_cast<uint2*>(dst + n) = cv.u;
    }
}

// ---------------------------------------------------------------------------
// fused coupling + transpose + gate:
//   Ag[(b*SN+n), ho*64+d] = ( sum_hi cw[ho][hi] * wave[b, hi*64+d, n] ) * gate[...]
// ---------------------------------------------------------------------------
__global__ __launch_bounds__(256) void couplegate_kernel(
        const __hip_bfloat16* __restrict__ wave,
        const float* __restrict__ cw,
        const __hip_bfloat16* __restrict__ gate,
        __hip_bfloat16* __restrict__ Ag) {
    const int b = blockIdx.y;
    const int n0 = blockIdx.x * 32;
    __shared__ unsigned short U[33 * 1024];   // 66 KB: Wl[1024][32] then Out[32][1032]
    __shared__ float cwl[NH * NH];
    const int t = threadIdx.x;
    const int wv = t >> 6, ln = t & 63;

    // stage wave tile, channel-major; slot qs holds global quad qs ^ (c&3)
    #pragma unroll
    for (int p = 0; p < 16; ++p) {
        const int u = p * 256 + wv * 64 + ln;     // 16B-unit index 0..4095
        const int cch = u >> 2, qs = u & 3;
        const int qg = qs ^ (cch & 3);
        async_load16(wave + (size_t)(b * DM + cch) * SN + n0 + qg * 8,
                     (char*)U + (size_t)(p * 256 + wv * 64) * 16);
    }
    cwl[t] = cw[t];
    __syncthreads();   // implies vmcnt(0): staged data valid

    // load inputs for both d-chunks into registers (all-static indexing)
    const int nq = t & 7;
    const int d0 = t >> 3;          // 0..31
    const int d1 = 32 + d0;         // 32..63
    float v0[16][4], v1[16][4];
    #pragma unroll
    for (int hi = 0; hi < 16; ++hi) {
        #pragma unroll
        for (int q = 0; q < 4; ++q) {
            const int s0 = q ^ (d0 & 3);
            const int s1 = q ^ (d1 & 3);
            v0[hi][q] = bf2f(U[(hi * 64 + d0) * 32 + s0 * 8 + nq]);
            v1[hi][q] = bf2f(U[(hi * 64 + d1) * 32 + s1 * 8 + nq]);
        }
    }
    __syncthreads();   // all Wl reads done; U becomes Out[32][1032]

    #pragma unroll
    for (int ho = 0; ho < 16; ++ho) {
        float cwr[16];
        #pragma unroll
        for (int j = 0; j < 4; ++j) {
            const float4 c4 = *reinterpret_cast<const float4*>(&cwl[ho * 16 + j * 4]);
            cwr[j * 4 + 0] = c4.x; cwr[j * 4 + 1] = c4.y;
            cwr[j * 4 + 2] = c4.z; cwr[j * 4 + 3] = c4.w;
        }
        float a0[4] = {0.f, 0.f, 0.f, 0.f}, a1[4] = {0.f, 0.f, 0.f, 0.f};
        #pragma unroll
        for (int hi = 0; hi < 16; ++hi) {
            #pragma unroll
            for (int q = 0; q < 4; ++q) {
                a0[q] += cwr[hi] * v0[hi][q];
                a1[q] += cwr[hi] * v1[hi][q];
            }
        }
        #pragma unroll
        for (int q = 0; q < 4; ++q) {
            const int nloc = q * 8 + nq;           // k-strided: conflict-free stores
            U[nloc * 1032 + ho * 64 + d0] = f2bfbits(a0[q]);
            U[nloc * 1032 + ho * 64 + d1] = f2bfbits(a1[q]);
        }
    }
    __syncthreads();

    // gate + write, fully coalesced (16B/lane)
    #pragma unroll
    for (int p = 0; p < 16; ++p) {
        const int idx = p * 256 + t;
        const int nloc = idx >> 7, cu = idx & 127;
        const short8 ov = *reinterpret_cast<const short8*>(&U[nloc * 1032 + cu * 8]);
        const size_t off = ((size_t)(b * SN + n0 + nloc)) * DM + cu * 8;
        const short8 gv = *reinterpret_cast<const short8*>(
            reinterpret_cast<const unsigned short*>(gate) + off);
        union { __hip_bfloat16 hh[8]; short8 s; } cv;
        #pragma unroll
        for (int j = 0; j < 8; ++j)
            cv.hh[j] = __float2bfloat16(bf2f(ov[j]) * bf2f(gv[j]));
        *reinterpret_cast<short8*>(reinterpret_cast<unsigned short*>(Ag) + off) = cv.s;
    }
}

// ---------------------------------------------------------------------------
// launch — ws footprint ~143.7 MB
// ---------------------------------------------------------------------------
extern "C" void kernel_launch(void* const* d_in, const int* in_sizes, int n_in,
                              void* d_out, int out_size, void* d_ws, size_t ws_size,
                              hipStream_t stream) {
    const float* x     = (const float*)d_in[0];
    const float* qkv_w = (const float*)d_in[1];
    const float* qkv_b = (const float*)d_in[2];
    const float* out_w = (const float*)d_in[3];
    const float* out_b = (const float*)d_in[4];
    const float* gate_w = (const float*)d_in[5];
    const float* gate_b = (const float*)d_in[6];
    const float* scale_gain = (const float*)d_in[7];
    const float* field_coupling = (const float*)d_in[8];

    char* ws = (char*)d_ws;
    const int M = BD * SN;          // 16384

    // ws layout (bytes)
    __hip_bfloat16* x_bf    = (__hip_bfloat16*)(ws);               // 33,554,432
    __hip_bfloat16* wkg_bf  = (__hip_bfloat16*)(ws + 33554432);    //  4,194,304  [2048,1024]: Wk | Wgate
    __hip_bfloat16* wv_bf   = (__hip_bfloat16*)(ws + 37748736);    //  2,097,152  [1024,1024]: Wv
    __hip_bfloat16* wo_bf   = (__hip_bfloat16*)(ws + 39845888);    //  2,097,152
    float* wtab             = (float*)(ws + 41943040);             //      1,536
    float* cwbuf            = (float*)(ws + 41944576);             //      1,024
    float* biascat          = (float*)(ws + 41945600);             //      8,192
    float* kmag             = (float*)(ws + 41953792);             //  1,048,576  [16][16384]
    __hip_bfloat16* fieldv  = (__hip_bfloat16*)(ws + 43002368);    // 33,554,432  [1024][16384]
    __hip_bfloat16* gate_bf = (__hip_bfloat16*)(ws + 76556800);    // 33,554,432
    __hip_bfloat16* wave_bf = (__hip_bfloat16*)(ws + 110111232);   // 33,554,432
    // aliases (lifetimes verified):
    __hip_bfloat16* Ag = x_bf;     // x dead after kg & v GEMMs
    float* out = (float*)d_out;

    // converts
    f2bf_kernel<<<(M * DM / 4 + 255) / 256, 256, 0, stream>>>(x, x_bf, M * DM / 4);
    f2bf_kernel<<<(DM * DM / 4 + 255) / 256, 256, 0, stream>>>(qkv_w + (size_t)DM * DM, wkg_bf, DM * DM / 4);
    f2bf_kernel<<<(DM * DM / 4 + 255) / 256, 256, 0, stream>>>(gate_w, wkg_bf + (size_t)DM * DM, DM * DM / 4);
    f2bf_kernel<<<(DM * DM / 4 + 255) / 256, 256, 0, stream>>>(qkv_w + (size_t)2 * DM * DM, wv_bf, DM * DM / 4);
    f2bf_kernel<<<(DM * DM / 4 + 255) / 256, 256, 0, stream>>>(out_w, wo_bf, DM * DM / 4);

    prep_kernel<<<1, 256, 0, stream>>>(scale_gain, field_coupling, qkv_b, gate_b,
                                       wtab, cwbuf, biascat);

    // kg GEMM: cols 0-1023 -> kmag only; cols 1024-2047 -> gate_bf (sigmoid)
    {
        dim3 grid(2 * DM / 256, M / 256);
        gemm256_kernel<<<grid, 512, 0, stream>>>(x_bf, wkg_bf, gate_bf, biascat, kmag,
                                                 M, 2 * DM, DM, 2);
    }
    // v GEMM (swapped): fieldv[c][r] = Wv @ x^T  (channel-major, no transpose needed)
    {
        dim3 grid(M / 256, DM / 256);
        gemm256_kernel<<<grid, 512, 0, stream>>>(wv_bf, x_bf, fieldv, qkv_b + 2 * DM, nullptr,
                                                 DM, M, DM, 1);
    }
    // wavelet (applies kmag inline)
    wavelet_kernel<<<BD * DM, 256, 0, stream>>>(fieldv, kmag, wtab, wave_bf);
    // fused coupling + transpose + gate -> Ag bf16 [16384, 1024]
    {
        dim3 grid(SN / 32, BD);
        couplegate_kernel<<<grid, 256, 0, stream>>>(wave_bf, cwbuf, gate_bf, Ag);
    }
    // out = Ag @ out_w^T + out_b   (fp32 -> d_out)
    {
        dim3 grid(DM / 256, M / 256);
        gemm256_kernel<<<grid, 512, 0, stream>>>(Ag, wo_bf, out, out_b, nullptr,
                                                 M, DM, DM, 0);
    }
}

// Round 5
// 385.724 us; speedup vs baseline: 1.1548x; 1.1548x over previous
//
#include <hip/hip_runtime.h>
#include <hip/hip_bf16.h>
#include <math.h>

// Problem constants
#define BD 8          // batch
#define SN 2048       // sequence length N
#define DM 1024       // d_model
#define NH 16         // heads
#define HD 64         // head dim
#define NS 11         // scales
#define NTAP 24       // unique wavelet offsets across 11 scales
#define PAD 3072      // max lookback = 3*2^10

typedef __attribute__((ext_vector_type(8))) short short8;
typedef __attribute__((ext_vector_type(4))) float floatx4;

// unique offsets (3-t)<<j, sorted
constexpr int OFFS[NTAP] = {0, 1, 2, 3, 4, 6, 8, 12, 16, 24, 32, 48, 64, 96,
                            128, 192, 256, 384, 512, 768, 1024, 1536, 2048, 3072};

// async global->LDS, 16B per lane; LDS dest = wave-uniform base + lane*16
__device__ __forceinline__ void async_load16(const void* g, void* lds) {
    __builtin_amdgcn_global_load_lds(
        (const __attribute__((address_space(1))) void*)g,
        (__attribute__((address_space(3))) void*)lds,
        16, 0, 0);
}

__device__ __forceinline__ float bf2f(int v) {
    union { unsigned u; float f; } cv;
    cv.u = ((unsigned)v & 0xffffu) << 16;
    return cv.f;
}

__device__ __forceinline__ unsigned short f2bfbits(float x) {
    union { __hip_bfloat16 h; unsigned short u; } cv;
    cv.h = __float2bfloat16(x);
    return cv.u;
}

// ---------------------------------------------------------------------------
// fp32 -> bf16 convert (vectorized by 4)
// ---------------------------------------------------------------------------
__global__ __launch_bounds__(256) void f2bf_kernel(const float* __restrict__ src,
                                                   __hip_bfloat16* __restrict__ dst,
                                                   int n4) {
    int i = blockIdx.x * 256 + threadIdx.x;
    if (i < n4) {
        const float4 v = reinterpret_cast<const float4*>(src)[i];
        union { __hip_bfloat16 h[4]; uint2 u; } cv;
        cv.h[0] = __float2bfloat16(v.x);
        cv.h[1] = __float2bfloat16(v.y);
        cv.h[2] = __float2bfloat16(v.z);
        cv.h[3] = __float2bfloat16(v.w);
        reinterpret_cast<uint2*>(dst)[i] = cv.u;
    }
}

// ---------------------------------------------------------------------------
// prep: softmaxes + per-head tap table + kg bias concat
// ---------------------------------------------------------------------------
__global__ void prep_kernel(const float* __restrict__ scale_gain,
                            const float* __restrict__ field_coupling,
                            const float* __restrict__ qkv_b,
                            const float* __restrict__ gate_b,
                            float* __restrict__ wtab,    // [NTAP][NH]
                            float* __restrict__ cw,      // [NH][NH]
                            float* __restrict__ biascat) // [2048]: k bias | gate bias
{
    const float D4[4] = {0.4829629131445341f, 0.8365163037378079f,
                         0.2241438680420134f, -0.1294095225512604f};
    int t = threadIdx.x;
    if (t < NH) {
        float g[NS];
        float m = -1e30f;
        for (int j = 0; j < NS; ++j) m = fmaxf(m, scale_gain[j * NH + t]);
        float s = 0.f;
        for (int j = 0; j < NS; ++j) { g[j] = expf(scale_gain[j * NH + t] - m); s += g[j]; }
        float inv = 1.f / s;
        for (int j = 0; j < NS; ++j) g[j] *= inv;
        for (int i = 0; i < NTAP; ++i) {
            float w = 0.f;
            for (int j = 0; j < NS; ++j)
                for (int tt = 0; tt < 4; ++tt)
                    if (((3 - tt) << j) == OFFS[i]) w += g[j] * D4[tt];
            wtab[i * NH + t] = w;
        }
    } else if (t < 2 * NH) {
        int r = t - NH;
        float m = -1e30f;
        for (int j = 0; j < NH; ++j) m = fmaxf(m, field_coupling[r * NH + j]);
        float e[NH]; float s = 0.f;
        for (int j = 0; j < NH; ++j) { e[j] = expf(field_coupling[r * NH + j] - m); s += e[j]; }
        float inv = 1.f / s;
        for (int j = 0; j < NH; ++j) cw[r * NH + j] = e[j] * inv;
    }
    for (int i = t; i < 2048; i += 256)
        biascat[i] = (i < 1024) ? qkv_b[1024 + i] : gate_b[i - 1024];
}

// ---------------------------------------------------------------------------
// m97-class bf16 MFMA GEMM, 128x128 tile, BK=64, XOR-swizzled global_load_lds.
// 1-D grid + XCD-aware swizzle (T1): hardware round-robins consecutive flat
// blockIdx over the 8 XCDs; swz = (flat&7)*cpx + flat>>3 gives each XCD a
// contiguous tile range (n fastest, m slow) -> A-panels + 4MB weights stay in
// the XCD-private L2. Bijective since every grid is a multiple of 8.
// mode 0: C fp32 = A@Bw^T + bias[col]                  (out GEMM)
// mode 1: C bf16 = A@Bw^T + bias[row]                  (v GEMM, swapped operands)
// mode 2: kg fused: cols<1024 -> kmag[h][r] = ||k+bias|| (no C write);
//         cols>=1024 -> gate bf16 = sigmoid(. + bias[col]), stored at col-1024
// ---------------------------------------------------------------------------
__global__ __launch_bounds__(256, 3) void gemm128_kernel(
    const __hip_bfloat16* __restrict__ A,
    const __hip_bfloat16* __restrict__ Bw,
    void* __restrict__ Cout,
    const float* __restrict__ bias,
    float* __restrict__ kmag,
    int M, int Nn, int K, int mode) {
    __shared__ short As[128 * 64];   // 16 KB, row stride 128B, swizzled
    __shared__ short Bs[128 * 64];

    const int tid = threadIdx.x;
    // XCD-aware decode (nwg % 8 == 0 for all call sites)
    const int nxb = Nn >> 7;
    const int flat = blockIdx.x;
    const int cpx = gridDim.x >> 3;
    const int swz = (flat & 7) * cpx + (flat >> 3);
    const int m0 = (swz / nxb) * 128;
    const int n0 = (swz % nxb) * 128;
    const int wv = tid >> 6;
    const int ln = tid & 63;

    const int srow = ln >> 3;
    const int scc  = (ln & 7) ^ srow;
    size_t goffA[4], goffB[4];
    #pragma unroll
    for (int i = 0; i < 4; ++i) {
        const int row = wv * 32 + i * 8 + srow;
        goffA[i] = (size_t)(m0 + row) * K + scc * 8;
        goffB[i] = (size_t)(n0 + row) * K + scc * 8;
    }

    const int lrow = ln & 15, quad = ln >> 4;
    const int wm = (wv >> 1) * 64;
    const int wn = (wv & 1) * 64;
    int aaddr[4], baddr[4];
    #pragma unroll
    for (int t = 0; t < 4; ++t) {
        const int sw = (quad ^ (lrow & 7)) * 16;
        aaddr[t] = (wm + t * 16 + lrow) * 128 + sw;
        baddr[t] = (wn + t * 16 + lrow) * 128 + sw;
    }

    floatx4 acc[4][4];
    #pragma unroll
    for (int a = 0; a < 4; ++a)
        #pragma unroll
        for (int b = 0; b < 4; ++b) acc[a][b] = (floatx4){0.f, 0.f, 0.f, 0.f};

    for (int kt = 0; kt < K; kt += 64) {
        #pragma unroll
        for (int i = 0; i < 4; ++i) {
            async_load16(A + goffA[i] + kt, &As[(wv * 32 + i * 8) * 64]);
            async_load16(Bw + goffB[i] + kt, &Bs[(wv * 32 + i * 8) * 64]);
        }
        __syncthreads();
        #pragma unroll
        for (int h = 0; h < 2; ++h) {
            short8 a[4], b[4];
            #pragma unroll
            for (int t = 0; t < 4; ++t) {
                a[t] = *reinterpret_cast<const short8*>(
                           reinterpret_cast<const char*>(As) + (aaddr[t] ^ (h * 64)));
                b[t] = *reinterpret_cast<const short8*>(
                           reinterpret_cast<const char*>(Bs) + (baddr[t] ^ (h * 64)));
            }
            #pragma unroll
            for (int mt = 0; mt < 4; ++mt)
                #pragma unroll
                for (int nt = 0; nt < 4; ++nt)
                    acc[mt][nt] = __builtin_amdgcn_mfma_f32_16x16x32_bf16(
                        a[mt], b[nt], acc[mt][nt], 0, 0, 0);
        }
        __syncthreads();
    }

    if (mode == 2 && n0 < 1024) {
        // k-norm epilogue: each wave's 64 cols = exactly one head
        const int h = (n0 + wn) >> 6;
        #pragma unroll
        for (int mt = 0; mt < 4; ++mt) {
            #pragma unroll
            for (int i = 0; i < 4; ++i) {
                float ss = 0.f;
                #pragma unroll
                for (int nt = 0; nt < 4; ++nt) {
                    const float v = acc[mt][nt][i] + bias[n0 + wn + nt * 16 + lrow];
                    ss += v * v;
                }
                ss += __shfl_xor(ss, 1);
                ss += __shfl_xor(ss, 2);
                ss += __shfl_xor(ss, 4);
                ss += __shfl_xor(ss, 8);
                if (lrow == 0) {
                    const int r = m0 + wm + mt * 16 + quad * 4 + i;
                    kmag[h * (BD * SN) + r] = sqrtf(ss);
                }
            }
        }
        return;
    }

    #pragma unroll
    for (int mt = 0; mt < 4; ++mt) {
        #pragma unroll
        for (int nt = 0; nt < 4; ++nt) {
            const int col = n0 + wn + nt * 16 + lrow;
            float bv = 0.f;
            if (bias && mode != 1) bv = bias[col];
            #pragma unroll
            for (int i = 0; i < 4; ++i) {
                const int row = m0 + wm + mt * 16 + quad * 4 + i;
                float val = acc[mt][nt][i] + bv;
                if (mode == 1 && bias) val += bias[row];
                if (mode == 0) {
                    ((float*)Cout)[(size_t)row * Nn + col] = val;
                } else if (mode == 1) {
                    ((__hip_bfloat16*)Cout)[(size_t)row * Nn + col] = __float2bfloat16(val);
                } else { // mode 2 gate region
                    val = 1.f / (1.f + expf(-val));
                    ((__hip_bfloat16*)Cout)[(size_t)row * 1024 + (col - 1024)] =
                        __float2bfloat16(val);
                }
            }
        }
    }
}

// ---------------------------------------------------------------------------
// wavelet v2: per (b,c) row; zero-padded LDS row + 24-tap table.
// Each thread computes 4 consecutive outputs via ds_read_b128 quad loads.
// ---------------------------------------------------------------------------
__global__ __launch_bounds__(256) void wavelet_kernel(const __hip_bfloat16* __restrict__ fieldv,
                                                      const float* __restrict__ kmag,
                                                      const float* __restrict__ wtab,
                                                      __hip_bfloat16* __restrict__ wave) {
    const int bc = blockIdx.x;          // b*1024 + c
    const int b = bc >> 10;
    const int c = bc & (DM - 1);
    const int h = c >> 6;
    __shared__ float row[PAD + SN];     // 20 KB
    const int t = threadIdx.x;

    // tap weights: uniform per block -> scalar loads
    float w[NTAP];
    #pragma unroll
    for (int i = 0; i < NTAP; ++i) w[i] = wtab[i * NH + h];

    // zero pad region: 3072 floats = 768 float4
    {
        float4* r4 = reinterpret_cast<float4*>(row);
        const float4 zv = {0.f, 0.f, 0.f, 0.f};
        #pragma unroll
        for (int i = 0; i < 3; ++i) r4[t + i * 256] = zv;
    }
    // fill: 8 elements per thread (vectorized bf16 load * fp32 kmag)
    {
        const __hip_bfloat16* src = fieldv + (size_t)c * (BD * SN) + b * SN;
        const float* mag = kmag + (size_t)h * (BD * SN) + b * SN;
        const int i = t * 8;
        const short8 s = *reinterpret_cast<const short8*>(src + i);
        const float4 m0 = *reinterpret_cast<const float4*>(mag + i);
        const float4 m1 = *reinterpret_cast<const float4*>(mag + i + 4);
        float4 o0, o1;
        o0.x = bf2f(s[0]) * m0.x; o0.y = bf2f(s[1]) * m0.y;
        o0.z = bf2f(s[2]) * m0.z; o0.w = bf2f(s[3]) * m0.w;
        o1.x = bf2f(s[4]) * m1.x; o1.y = bf2f(s[5]) * m1.y;
        o1.z = bf2f(s[6]) * m1.z; o1.w = bf2f(s[7]) * m1.w;
        *reinterpret_cast<float4*>(&row[PAD + i]) = o0;
        *reinterpret_cast<float4*>(&row[PAD + i + 4]) = o1;
    }
    __syncthreads();

    __hip_bfloat16* dst = wave + (size_t)bc * SN;
    #pragma unroll
    for (int pass = 0; pass < 2; ++pass) {
        const int n = (pass * 256 + t) * 4;
        const float* bp = &row[PAD + n];
        const float4 qc = *reinterpret_cast<const float4*>(bp);       // row[n..n+3]
        const float4 qb = *reinterpret_cast<const float4*>(bp - 4);   // row[n-4..n-1]
        const float4 qa = *reinterpret_cast<const float4*>(bp - 8);   // row[n-8..n-5]
        float a0, a1, a2, a3;
        a0 = w[0] * qc.x; a1 = w[0] * qc.y; a2 = w[0] * qc.z; a3 = w[0] * qc.w;
        a0 += w[1] * qb.w; a1 += w[1] * qc.x; a2 += w[1] * qc.y; a3 += w[1] * qc.z;
        a0 += w[2] * qb.z; a1 += w[2] * qb.w; a2 += w[2] * qc.x; a3 += w[2] * qc.y;
        a0 += w[3] * qb.y; a1 += w[3] * qb.z; a2 += w[3] * qb.w; a3 += w[3] * qc.x;
        a0 += w[4] * qb.x; a1 += w[4] * qb.y; a2 += w[4] * qb.z; a3 += w[4] * qb.w;
        a0 += w[5] * qa.z; a1 += w[5] * qa.w; a2 += w[5] * qb.x; a3 += w[5] * qb.y;
        a0 += w[6] * qa.x; a1 += w[6] * qa.y; a2 += w[6] * qa.z; a3 += w[6] * qa.w;
        #pragma unroll
        for (int i = 7; i < NTAP; ++i) {
            const float4 q = *reinterpret_cast<const float4*>(bp - OFFS[i]);
            a0 += w[i] * q.x; a1 += w[i] * q.y; a2 += w[i] * q.z; a3 += w[i] * q.w;
        }
        union { __hip_bfloat16 hh[4]; uint2 u; } cv;
        cv.hh[0] = __float2bfloat16(a0); cv.hh[1] = __float2bfloat16(a1);
        cv.hh[2] = __float2bfloat16(a2); cv.hh[3] = __float2bfloat16(a3);
        *reinterpret_cast<uint2*>(dst + n) = cv.u;
    }
}

// ---------------------------------------------------------------------------
// fused coupling + transpose + gate:
//   Ag[(b*SN+n), ho*64+d] = ( sum_hi cw[ho][hi] * wave[b, hi*64+d, n] ) * gate[...]
// ---------------------------------------------------------------------------
__global__ __launch_bounds__(256) void couplegate_kernel(
        const __hip_bfloat16* __restrict__ wave,
        const float* __restrict__ cw,
        const __hip_bfloat16* __restrict__ gate,
        __hip_bfloat16* __restrict__ Ag) {
    const int b = blockIdx.y;
    const int n0 = blockIdx.x * 32;
    __shared__ unsigned short U[33 * 1024];   // 66 KB: Wl[1024][32] then Out[32][1032]
    __shared__ float cwl[NH * NH];
    const int t = threadIdx.x;
    const int wv = t >> 6, ln = t & 63;

    // stage wave tile, channel-major; slot qs holds global quad qs ^ (c&3)
    #pragma unroll
    for (int p = 0; p < 16; ++p) {
        const int u = p * 256 + wv * 64 + ln;     // 16B-unit index 0..4095
        const int cch = u >> 2, qs = u & 3;
        const int qg = qs ^ (cch & 3);
        async_load16(wave + (size_t)(b * DM + cch) * SN + n0 + qg * 8,
                     (char*)U + (size_t)(p * 256 + wv * 64) * 16);
    }
    cwl[t] = cw[t];
    __syncthreads();   // implies vmcnt(0): staged data valid

    // load inputs for both d-chunks into registers (all-static indexing)
    const int nq = t & 7;
    const int d0 = t >> 3;          // 0..31
    const int d1 = 32 + d0;         // 32..63
    float v0[16][4], v1[16][4];
    #pragma unroll
    for (int hi = 0; hi < 16; ++hi) {
        #pragma unroll
        for (int q = 0; q < 4; ++q) {
            const int s0 = q ^ (d0 & 3);
            const int s1 = q ^ (d1 & 3);
            v0[hi][q] = bf2f(U[(hi * 64 + d0) * 32 + s0 * 8 + nq]);
            v1[hi][q] = bf2f(U[(hi * 64 + d1) * 32 + s1 * 8 + nq]);
        }
    }
    __syncthreads();   // all Wl reads done; U becomes Out[32][1032]

    #pragma unroll
    for (int ho = 0; ho < 16; ++ho) {
        float cwr[16];
        #pragma unroll
        for (int j = 0; j < 4; ++j) {
            const float4 c4 = *reinterpret_cast<const float4*>(&cwl[ho * 16 + j * 4]);
            cwr[j * 4 + 0] = c4.x; cwr[j * 4 + 1] = c4.y;
            cwr[j * 4 + 2] = c4.z; cwr[j * 4 + 3] = c4.w;
        }
        float a0[4] = {0.f, 0.f, 0.f, 0.f}, a1[4] = {0.f, 0.f, 0.f, 0.f};
        #pragma unroll
        for (int hi = 0; hi < 16; ++hi) {
            #pragma unroll
            for (int q = 0; q < 4; ++q) {
                a0[q] += cwr[hi] * v0[hi][q];
                a1[q] += cwr[hi] * v1[hi][q];
            }
        }
        #pragma unroll
        for (int q = 0; q < 4; ++q) {
            const int nloc = q * 8 + nq;           // k-strided: conflict-free stores
            U[nloc * 1032 + ho * 64 + d0] = f2bfbits(a0[q]);
            U[nloc * 1032 + ho * 64 + d1] = f2bfbits(a1[q]);
        }
    }
    __syncthreads();

    // gate + write, fully coalesced (16B/lane)
    #pragma unroll
    for (int p = 0; p < 16; ++p) {
        const int idx = p * 256 + t;
        const int nloc = idx >> 7, cu = idx & 127;
        const short8 ov = *reinterpret_cast<const short8*>(&U[nloc * 1032 + cu * 8]);
        const size_t off = ((size_t)(b * SN + n0 + nloc)) * DM + cu * 8;
        const short8 gv = *reinterpret_cast<const short8*>(
            reinterpret_cast<const unsigned short*>(gate) + off);
        union { __hip_bfloat16 hh[8]; short8 s; } cv;
        #pragma unroll
        for (int j = 0; j < 8; ++j)
            cv.hh[j] = __float2bfloat16(bf2f(ov[j]) * bf2f(gv[j]));
        *reinterpret_cast<short8*>(reinterpret_cast<unsigned short*>(Ag) + off) = cv.s;
    }
}

// ---------------------------------------------------------------------------
// launch — ws footprint ~143.7 MB
// ---------------------------------------------------------------------------
extern "C" void kernel_launch(void* const* d_in, const int* in_sizes, int n_in,
                              void* d_out, int out_size, void* d_ws, size_t ws_size,
                              hipStream_t stream) {
    const float* x     = (const float*)d_in[0];
    const float* qkv_w = (const float*)d_in[1];
    const float* qkv_b = (const float*)d_in[2];
    const float* out_w = (const float*)d_in[3];
    const float* out_b = (const float*)d_in[4];
    const float* gate_w = (const float*)d_in[5];
    const float* gate_b = (const float*)d_in[6];
    const float* scale_gain = (const float*)d_in[7];
    const float* field_coupling = (const float*)d_in[8];

    char* ws = (char*)d_ws;
    const int M = BD * SN;          // 16384

    // ws layout (bytes)
    __hip_bfloat16* x_bf    = (__hip_bfloat16*)(ws);               // 33,554,432
    __hip_bfloat16* wkg_bf  = (__hip_bfloat16*)(ws + 33554432);    //  4,194,304  [2048,1024]: Wk | Wgate
    __hip_bfloat16* wv_bf   = (__hip_bfloat16*)(ws + 37748736);    //  2,097,152  [1024,1024]: Wv
    __hip_bfloat16* wo_bf   = (__hip_bfloat16*)(ws + 39845888);    //  2,097,152
    float* wtab             = (float*)(ws + 41943040);             //      1,536
    float* cwbuf            = (float*)(ws + 41944576);             //      1,024
    float* biascat          = (float*)(ws + 41945600);             //      8,192
    float* kmag             = (float*)(ws + 41953792);             //  1,048,576  [16][16384]
    __hip_bfloat16* fieldv  = (__hip_bfloat16*)(ws + 43002368);    // 33,554,432  [1024][16384]
    __hip_bfloat16* gate_bf = (__hip_bfloat16*)(ws + 76556800);    // 33,554,432
    __hip_bfloat16* wave_bf = (__hip_bfloat16*)(ws + 110111232);   // 33,554,432
    // aliases (lifetimes verified):
    __hip_bfloat16* Ag = x_bf;     // x dead after kg & v GEMMs
    float* out = (float*)d_out;

    // converts
    f2bf_kernel<<<(M * DM / 4 + 255) / 256, 256, 0, stream>>>(x, x_bf, M * DM / 4);
    f2bf_kernel<<<(DM * DM / 4 + 255) / 256, 256, 0, stream>>>(qkv_w + (size_t)DM * DM, wkg_bf, DM * DM / 4);
    f2bf_kernel<<<(DM * DM / 4 + 255) / 256, 256, 0, stream>>>(gate_w, wkg_bf + (size_t)DM * DM, DM * DM / 4);
    f2bf_kernel<<<(DM * DM / 4 + 255) / 256, 256, 0, stream>>>(qkv_w + (size_t)2 * DM * DM, wv_bf, DM * DM / 4);
    f2bf_kernel<<<(DM * DM / 4 + 255) / 256, 256, 0, stream>>>(out_w, wo_bf, DM * DM / 4);

    prep_kernel<<<1, 256, 0, stream>>>(scale_gain, field_coupling, qkv_b, gate_b,
                                       wtab, cwbuf, biascat);

    // kg GEMM: cols 0-1023 -> kmag only; cols 1024-2047 -> gate_bf (sigmoid)
    {
        const int nwg = (2 * DM / 128) * (M / 128);   // 2048
        gemm128_kernel<<<nwg, 256, 0, stream>>>(x_bf, wkg_bf, gate_bf, biascat, kmag,
                                                M, 2 * DM, DM, 2);
    }
    // v GEMM (swapped): fieldv[c][r] = Wv @ x^T  (channel-major, no transpose needed)
    {
        const int nwg = (M / 128) * (DM / 128);       // 1024
        gemm128_kernel<<<nwg, 256, 0, stream>>>(wv_bf, x_bf, fieldv, qkv_b + 2 * DM, nullptr,
                                                DM, M, DM, 1);
    }
    // wavelet (applies kmag inline)
    wavelet_kernel<<<BD * DM, 256, 0, stream>>>(fieldv, kmag, wtab, wave_bf);
    // fused coupling + transpose + gate -> Ag bf16 [16384, 1024]
    {
        dim3 grid(SN / 32, BD);
        couplegate_kernel<<<grid, 256, 0, stream>>>(wave_bf, cwbuf, gate_bf, Ag);
    }
    // out = Ag @ out_w^T + out_b   (fp32 -> d_out)
    {
        const int nwg = (DM / 128) * (M / 128);       // 1024
        gemm128_kernel<<<nwg, 256, 0, stream>>>(Ag, wo_bf, out, out_b, nullptr,
                                                M, DM, DM, 0);
    }
}